// Round 5
// baseline (190.655 us; speedup 1.0000x reference)
//
#include <hip/hip_runtime.h>
#include <math.h>

// Backflow: out[i] = xi(|x_i|,t)*x_i + sum_j eta(|x_i-x_j|,t)*(x_i-x_j)
// t is scalar -> eta(r) is 1-D. Dense table (2049 pts over [0,16], linear
// interp) replaces 1M MLP evals. Total ~110us is ~90% fixed harness overhead
// (268MB d_ws re-poison = 39.5us @ 85% HBM peak + ~16 restore dispatches);
// controllable kernel time ~10us.
//
// R4: fuse the two kernels into one launch. Blocks 0..48 produce (eta table ->
// ws, one-body -> ws.obb), blocks 49..304 consume (two-body + final out write).
// Handshake: per-producer MAGIC flags in ws, device-scope release/acquire.
// Deadlock-safe by capacity: LDS 20.5KB, VGPR ~76 -> >=4 blocks/CU -> >=1024
// resident slots >> 305 blocks; producers never wait. Single-writer out:
// consumers write out = obb + twobody. Fast softplus __logf(1+__expf(v))
// (args in [1.5,5], err ~1e-7 << 1.235 threshold).

#define TABLE_N 2048
#define RMAX 16.0f
#define NPART 1024
#define TBLOCKS 33                  // ceil(2049/64) table blocks
#define OBLOCKS 16                  // 1024/64 one-body blocks
#define PBLOCKS (TBLOCKS + OBLOCKS) // 49 producers
#define CBLOCKS 256                 // two-body consumers (4 rows each)
#define MAGIC 0x5EEDF00D
// ws float layout: table[0..2049) | pad | obb @ 2112 (3072) | flags @ 5184 (49 ints)
#define OBB_OFF 2112
#define FLAG_OFF 5184

__device__ __forceinline__ float sp_fast(float v) {
    // softplus; v in [-1,2] here so no range fixups needed
    return __logf(1.f + __expf(v));
}

union SMem {
    struct {                          // producer view (18.7 KB)
        float w2s[4096];
        float w1s[128];
        float b1s[64];
        float b2s[64];
        float w3s[64];
        float partial[4][64];
    } p;
    struct {                          // consumer view (20.5 KB)
        float xs[NPART], ys[NPART], zs[NPART];
        float tab[2052];
    } c;
};

__global__ __launch_bounds__(256) void fused_backflow(
    const float* __restrict__ x, const float* __restrict__ t_ptr,
    const float* __restrict__ xiW1, const float* __restrict__ xib1,
    const float* __restrict__ xiW2, const float* __restrict__ xib2,
    const float* __restrict__ xiW3, const float* __restrict__ xib3,
    const float* __restrict__ eW1,  const float* __restrict__ eb1,
    const float* __restrict__ eW2,  const float* __restrict__ eb2,
    const float* __restrict__ eW3,  const float* __restrict__ eb3,
    float* __restrict__ out, float* __restrict__ ws)
{
    __shared__ __align__(16) SMem sm;
    float* __restrict__ table = ws;
    float* __restrict__ obb   = ws + OBB_OFF;
    int*   flags              = (int*)(ws + FLAG_OFF);

    const int tid  = threadIdx.x;
    const int b    = blockIdx.x;
    const int lane = tid & 63;
    const int w    = tid >> 6;

    if (b < PBLOCKS) {
        // ---------------- producer: table entries or one-body rows ----------
        const bool tb = (b < TBLOCKS);
        const float* __restrict__ W1 = tb ? eW1 : xiW1;
        const float* __restrict__ B1 = tb ? eb1 : xib1;
        const float* __restrict__ W2 = tb ? eW2 : xiW2;
        const float* __restrict__ B2 = tb ? eb2 : xib2;
        const float* __restrict__ W3 = tb ? eW3 : xiW3;

        {   // bulk-stage weights into LDS
            const float4* src = (const float4*)W2;
            float4* dst = (float4*)sm.p.w2s;
            #pragma unroll
            for (int i2 = 0; i2 < 4; ++i2) dst[tid + 256 * i2] = src[tid + 256 * i2];
            if (tid < 128)      sm.p.w1s[tid]       = W1[tid];
            else if (tid < 192) sm.p.b1s[tid - 128] = B1[tid - 128];
            else                sm.p.b2s[tid - 192] = B2[tid - 192];
            if (tid < 64)       sm.p.w3s[tid]       = W3[tid];
        }

        const float t = t_ptr[0];
        const int mo  = w * 16;
        float r, xx = 0.f, xy = 0.f, xz = 0.f;
        int i_row = 0;
        if (tb) {
            int e = b * 64 + lane;
            r = (float)e * (RMAX / (float)TABLE_N);
        } else {
            i_row = (b - TBLOCKS) * 64 + lane;
            xx = x[3 * i_row]; xy = x[3 * i_row + 1]; xz = x[3 * i_row + 2];
            r = sqrtf(fmaf(xx, xx, fmaf(xy, xy, xz * xz)));
        }
        __syncthreads();

        float4 z0 = ((const float4*)(sm.p.b2s + mo))[0];
        float4 z1 = ((const float4*)(sm.p.b2s + mo))[1];
        float4 z2 = ((const float4*)(sm.p.b2s + mo))[2];
        float4 z3 = ((const float4*)(sm.p.b2s + mo))[3];
        for (int k = 0; k < 64; ++k) {
            float h = sp_fast(fmaf(r, sm.p.w1s[k], fmaf(t, sm.p.w1s[64 + k], sm.p.b1s[k])));
            const float4* wr = (const float4*)(sm.p.w2s + k * 64 + mo);
            float4 a0 = wr[0], a1 = wr[1], a2 = wr[2], a3 = wr[3];
            z0.x = fmaf(h, a0.x, z0.x); z0.y = fmaf(h, a0.y, z0.y);
            z0.z = fmaf(h, a0.z, z0.z); z0.w = fmaf(h, a0.w, z0.w);
            z1.x = fmaf(h, a1.x, z1.x); z1.y = fmaf(h, a1.y, z1.y);
            z1.z = fmaf(h, a1.z, z1.z); z1.w = fmaf(h, a1.w, z1.w);
            z2.x = fmaf(h, a2.x, z2.x); z2.y = fmaf(h, a2.y, z2.y);
            z2.z = fmaf(h, a2.z, z2.z); z2.w = fmaf(h, a2.w, z2.w);
            z3.x = fmaf(h, a3.x, z3.x); z3.y = fmaf(h, a3.y, z3.y);
            z3.z = fmaf(h, a3.z, z3.z); z3.w = fmaf(h, a3.w, z3.w);
        }
        float p = 0.f;
        p = fmaf(sp_fast(z0.x), sm.p.w3s[mo + 0],  p); p = fmaf(sp_fast(z0.y), sm.p.w3s[mo + 1],  p);
        p = fmaf(sp_fast(z0.z), sm.p.w3s[mo + 2],  p); p = fmaf(sp_fast(z0.w), sm.p.w3s[mo + 3],  p);
        p = fmaf(sp_fast(z1.x), sm.p.w3s[mo + 4],  p); p = fmaf(sp_fast(z1.y), sm.p.w3s[mo + 5],  p);
        p = fmaf(sp_fast(z1.z), sm.p.w3s[mo + 6],  p); p = fmaf(sp_fast(z1.w), sm.p.w3s[mo + 7],  p);
        p = fmaf(sp_fast(z2.x), sm.p.w3s[mo + 8],  p); p = fmaf(sp_fast(z2.y), sm.p.w3s[mo + 9],  p);
        p = fmaf(sp_fast(z2.z), sm.p.w3s[mo + 10], p); p = fmaf(sp_fast(z2.w), sm.p.w3s[mo + 11], p);
        p = fmaf(sp_fast(z3.x), sm.p.w3s[mo + 12], p); p = fmaf(sp_fast(z3.y), sm.p.w3s[mo + 13], p);
        p = fmaf(sp_fast(z3.z), sm.p.w3s[mo + 14], p); p = fmaf(sp_fast(z3.w), sm.p.w3s[mo + 15], p);

        sm.p.partial[w][lane] = p;
        __syncthreads();
        if (w == 0) {
            float f = sm.p.partial[0][lane] + sm.p.partial[1][lane]
                    + sm.p.partial[2][lane] + sm.p.partial[3][lane];
            if (tb) {
                int e = b * 64 + lane;
                if (e <= TABLE_N) table[e] = f + eb3[0];
            } else {
                f += xib3[0];
                obb[3 * i_row]     = f * xx;
                obb[3 * i_row + 1] = f * xy;
                obb[3 * i_row + 2] = f * xz;
            }
            __threadfence();
            if (lane == 0)
                __hip_atomic_store(&flags[b], MAGIC, __ATOMIC_RELEASE,
                                   __HIP_MEMORY_SCOPE_AGENT);
        }
    } else {
        // ---------------- consumer: two-body rows + final out write ---------
        // stage x first (overlaps producer compute)
        for (int idx = tid; idx < 3 * NPART; idx += 256) {
            float v = x[idx];
            int j = idx / 3, c = idx - 3 * j;
            if (c == 0) sm.c.xs[j] = v;
            else if (c == 1) sm.c.ys[j] = v;
            else sm.c.zs[j] = v;
        }
        // wait for all producers (table + one-body)
        if (tid == 0) {
            for (int f = 0; f < PBLOCKS; ++f)
                while (__hip_atomic_load(&flags[f], __ATOMIC_ACQUIRE,
                                         __HIP_MEMORY_SCOPE_AGENT) != MAGIC)
                    __builtin_amdgcn_s_sleep(2);
        }
        __syncthreads();
        {   // stage table: 2052 floats = 513 float4 (last 3 are pad, never read)
            const float4* src = (const float4*)table;
            float4* dst = (float4*)sm.c.tab;
            for (int i2 = tid; i2 < 513; i2 += 256) dst[i2] = src[i2];
        }
        __syncthreads();

        const int i = (b - PBLOCKS) * 4 + w;   // row 0..1023
        const float xi = sm.c.xs[i], yi = sm.c.ys[i], zi = sm.c.zs[i];
        float ax = 0.f, ay = 0.f, az = 0.f;
        const float scale = (float)TABLE_N / RMAX;  // 128
        #pragma unroll
        for (int it = 0; it < NPART / 64; ++it) {
            int j = it * 64 + lane;
            float dx = xi - sm.c.xs[j], dy = yi - sm.c.ys[j], dz = zi - sm.c.zs[j];
            float r = sqrtf(fmaf(dx, dx, fmaf(dy, dy, dz * dz)));
            float u = fminf(r * scale, (float)TABLE_N - 0.001f);
            int i0 = (int)u;
            float fr = u - (float)i0;
            float t0 = sm.c.tab[i0], t1 = sm.c.tab[i0 + 1];
            float f = fmaf(fr, t1 - t0, t0);
            ax = fmaf(f, dx, ax);
            ay = fmaf(f, dy, ay);
            az = fmaf(f, dz, az);
        }
        #pragma unroll
        for (int off = 32; off > 0; off >>= 1) {
            ax += __shfl_xor(ax, off);
            ay += __shfl_xor(ay, off);
            az += __shfl_xor(az, off);
        }
        if (lane == 0) {
            out[3 * i]     = obb[3 * i]     + ax;
            out[3 * i + 1] = obb[3 * i + 1] + ay;
            out[3 * i + 2] = obb[3 * i + 2] + az;
        }
    }
}

extern "C" void kernel_launch(void* const* d_in, const int* in_sizes, int n_in,
                              void* d_out, int out_size, void* d_ws, size_t ws_size,
                              hipStream_t stream) {
    const float* x     = (const float*)d_in[0];
    const float* t     = (const float*)d_in[1];
    const float* xiW1  = (const float*)d_in[2];
    const float* xib1  = (const float*)d_in[3];
    const float* xiW2  = (const float*)d_in[4];
    const float* xib2  = (const float*)d_in[5];
    const float* xiW3  = (const float*)d_in[6];
    const float* xib3  = (const float*)d_in[7];
    const float* eW1   = (const float*)d_in[8];
    const float* eb1   = (const float*)d_in[9];
    const float* eW2   = (const float*)d_in[10];
    const float* eb2   = (const float*)d_in[11];
    const float* eW3   = (const float*)d_in[12];
    const float* eb3   = (const float*)d_in[13];
    float* out = (float*)d_out;
    float* ws  = (float*)d_ws;

    fused_backflow<<<PBLOCKS + CBLOCKS, 256, 0, stream>>>(
        x, t, xiW1, xib1, xiW2, xib2, xiW3, xib3,
        eW1, eb1, eW2, eb2, eW3, eb3, out, ws);
}

// Round 6
// 91.251 us; speedup vs baseline: 2.0894x; 2.0894x over previous
//
#include <hip/hip_runtime.h>
#include <math.h>

// Backflow: out[i] = xi(|x_i|,t)*x_i + sum_j eta(|x_i-x_j|,t)*(x_i-x_j)
// t scalar -> eta(r) is 1-D: dense table (2049 pts over [0,16], linear interp)
// replaces 1M MLP evals. Fixed harness overhead H ~= 72.7us (268MB ws fill =
// 39.5us + restores); controllable kernel time is the rest.
//
// R4 FAILED: fusing producer+consumer made regalloc cap VGPR=36 -> producer
// spilled (118us). Reverted to two launches.
// R5: k1 restructured wave-parallel: one eval per wave (lane k computes h_k,
// lane m accumulates z_m; h via per-wave LDS, W2 conflict-free stride-1 LDS,
// shuffle-reduce epilogue). Two evals share W2 reads. No per-thread arrays ->
// nothing to spill; serial chain 1024 FMA -> 64 FMA.

#define TABLE_N 2048
#define RMAX 16.0f
#define NPART 1024
#define EB 129               // eta blocks: 129*16 = 2064 >= 2049 evals
#define XB 64                // xi blocks:  64*16  = 1024 rows
#define DELTA (RMAX / (float)TABLE_N)

__device__ __forceinline__ float sp_fast(float v) {
    // softplus; preacts here are in a tame range, no fixups needed
    return __logf(1.f + __expf(v));
}

// One wave handles 4 evals (2 pairs). Block = 4 waves = 16 evals.
// blocks 0..128: eta table -> ws   blocks 129..192: one-body -> out
__global__ __launch_bounds__(256) void k1_table_onebody(
    const float* __restrict__ x, const float* __restrict__ t_ptr,
    const float* __restrict__ xiW1, const float* __restrict__ xib1,
    const float* __restrict__ xiW2, const float* __restrict__ xib2,
    const float* __restrict__ xiW3, const float* __restrict__ xib3,
    const float* __restrict__ eW1,  const float* __restrict__ eb1,
    const float* __restrict__ eW2,  const float* __restrict__ eb2,
    const float* __restrict__ eW3,  const float* __restrict__ eb3,
    float* __restrict__ out, float* __restrict__ table)
{
    __shared__ __align__(16) float w2s[4096];   // W2 (64x64), 16 KB
    __shared__ __align__(16) float w1s[128];
    __shared__ __align__(16) float b1s[64];
    __shared__ __align__(16) float b2s[64];
    __shared__ __align__(16) float w3s[64];
    __shared__ __align__(16) float hbuf[4][128]; // per-wave h for 2 evals

    const int tid = threadIdx.x;
    const int b   = blockIdx.x;
    const bool tb = (b < EB);

    const float* __restrict__ W1 = tb ? eW1 : xiW1;
    const float* __restrict__ B1 = tb ? eb1 : xib1;
    const float* __restrict__ W2 = tb ? eW2 : xiW2;
    const float* __restrict__ B2 = tb ? eb2 : xib2;
    const float* __restrict__ W3 = tb ? eW3 : xiW3;

    {   // bulk-stage weights into LDS
        const float4* src = (const float4*)W2;
        float4* dst = (float4*)w2s;
        #pragma unroll
        for (int i2 = 0; i2 < 4; ++i2) dst[tid + 256 * i2] = src[tid + 256 * i2];
        if (tid < 128)      w1s[tid]       = W1[tid];
        else if (tid < 192) b1s[tid - 128] = B1[tid - 128];
        else                b2s[tid - 192] = B2[tid - 192];
        if (tid < 64)       w3s[tid]       = W3[tid];
    }

    const float t  = t_ptr[0];
    const float B3 = tb ? eb3[0] : xib3[0];
    const int lane = tid & 63;
    const int w    = tid >> 6;
    // eval base for this wave (eta: table index; xi: row index)
    const int base = tb ? (16 * b + 4 * w) : (16 * (b - EB) + 4 * w);

    __syncthreads();

    #pragma unroll
    for (int p = 0; p < 2; ++p) {
        const int e0 = base + 2 * p, e1 = e0 + 1;
        float r0, r1;
        float x0x = 0.f, x0y = 0.f, x0z = 0.f, x1x = 0.f, x1y = 0.f, x1z = 0.f;
        if (tb) {
            r0 = (float)e0 * DELTA;          // invalid e>2048 computed, write-guarded
            r1 = (float)e1 * DELTA;
        } else {
            x0x = x[3 * e0]; x0y = x[3 * e0 + 1]; x0z = x[3 * e0 + 2];
            x1x = x[3 * e1]; x1y = x[3 * e1 + 1]; x1z = x[3 * e1 + 2];
            r0 = sqrtf(fmaf(x0x, x0x, fmaf(x0y, x0y, x0z * x0z)));
            r1 = sqrtf(fmaf(x1x, x1x, fmaf(x1y, x1y, x1z * x1z)));
        }
        // phase A: lane k computes h_k for both evals (wave-private LDS, no barrier)
        const float w1a = w1s[lane], w1b = w1s[64 + lane], b1v = b1s[lane];
        hbuf[w][lane]      = sp_fast(fmaf(r0, w1a, fmaf(t, w1b, b1v)));
        hbuf[w][64 + lane] = sp_fast(fmaf(r1, w1a, fmaf(t, w1b, b1v)));
        // phase B: lane m accumulates z_m for both evals; W2 reads shared
        float z0 = b2s[lane], z1 = z0;
        #pragma unroll
        for (int k = 0; k < 64; k += 4) {
            float4 ha = *(const float4*)&hbuf[w][k];
            float4 hb = *(const float4*)&hbuf[w][64 + k];
            float wa = w2s[k * 64 + lane];
            float wbv = w2s[(k + 1) * 64 + lane];
            float wc = w2s[(k + 2) * 64 + lane];
            float wd = w2s[(k + 3) * 64 + lane];
            z0 = fmaf(ha.x, wa,  z0); z1 = fmaf(hb.x, wa,  z1);
            z0 = fmaf(ha.y, wbv, z0); z1 = fmaf(hb.y, wbv, z1);
            z0 = fmaf(ha.z, wc,  z0); z1 = fmaf(hb.z, wc,  z1);
            z0 = fmaf(ha.w, wd,  z0); z1 = fmaf(hb.w, wd,  z1);
        }
        // epilogue: p_m = softplus(z_m) * W3[m]; reduce across wave
        float q0 = sp_fast(z0) * w3s[lane];
        float q1 = sp_fast(z1) * w3s[lane];
        #pragma unroll
        for (int off = 32; off > 0; off >>= 1) {
            q0 += __shfl_xor(q0, off);
            q1 += __shfl_xor(q1, off);
        }
        if (lane == 0) {
            if (tb) {
                if (e0 <= TABLE_N) table[e0] = q0 + B3;
                if (e1 <= TABLE_N) table[e1] = q1 + B3;
            } else {
                float f0 = q0 + B3, f1 = q1 + B3;
                out[3 * e0] = f0 * x0x; out[3 * e0 + 1] = f0 * x0y; out[3 * e0 + 2] = f0 * x0z;
                out[3 * e1] = f1 * x1x; out[3 * e1 + 1] = f1 * x1y; out[3 * e1 + 2] = f1 * x1z;
            }
        }
    }
}

// One wave per row i; lane handles 16 j's. Diagonal j==i: r=0 -> f*0 = 0.
__global__ __launch_bounds__(256) void k2_twobody(
    const float* __restrict__ x, const float* __restrict__ table,
    float* __restrict__ out)
{
    __shared__ float xs[NPART], ys[NPART], zs[NPART];
    __shared__ __align__(16) float tab[2052];
    const int tid = threadIdx.x;

    for (int idx = tid; idx < 3 * NPART; idx += 256) {
        float v = x[idx];
        int j = idx / 3, c = idx - 3 * j;
        if (c == 0) xs[j] = v;
        else if (c == 1) ys[j] = v;
        else zs[j] = v;
    }
    {   // 2052 floats = 513 float4 (last 3 beyond table[2048] never read)
        const float4* src = (const float4*)table;
        float4* dst = (float4*)tab;
        for (int i2 = tid; i2 < 513; i2 += 256) dst[i2] = src[i2];
    }
    __syncthreads();

    const int wave = tid >> 6, lane = tid & 63;
    const int i = blockIdx.x * 4 + wave;
    const float xi = xs[i], yi = ys[i], zi = zs[i];
    float ax = 0.f, ay = 0.f, az = 0.f;
    const float scale = (float)TABLE_N / RMAX;
    #pragma unroll
    for (int it = 0; it < NPART / 64; ++it) {
        int j = it * 64 + lane;
        float dx = xi - xs[j], dy = yi - ys[j], dz = zi - zs[j];
        float r = sqrtf(fmaf(dx, dx, fmaf(dy, dy, dz * dz)));
        float u = fminf(r * scale, (float)TABLE_N - 0.001f);
        int i0 = (int)u;
        float fr = u - (float)i0;
        float t0 = tab[i0], t1 = tab[i0 + 1];
        float f = fmaf(fr, t1 - t0, t0);
        ax = fmaf(f, dx, ax);
        ay = fmaf(f, dy, ay);
        az = fmaf(f, dz, az);
    }
    #pragma unroll
    for (int off = 32; off > 0; off >>= 1) {
        ax += __shfl_xor(ax, off);
        ay += __shfl_xor(ay, off);
        az += __shfl_xor(az, off);
    }
    if (lane == 0) {
        out[3 * i]     += ax;
        out[3 * i + 1] += ay;
        out[3 * i + 2] += az;
    }
}

extern "C" void kernel_launch(void* const* d_in, const int* in_sizes, int n_in,
                              void* d_out, int out_size, void* d_ws, size_t ws_size,
                              hipStream_t stream) {
    const float* x     = (const float*)d_in[0];
    const float* t     = (const float*)d_in[1];
    const float* xiW1  = (const float*)d_in[2];
    const float* xib1  = (const float*)d_in[3];
    const float* xiW2  = (const float*)d_in[4];
    const float* xib2  = (const float*)d_in[5];
    const float* xiW3  = (const float*)d_in[6];
    const float* xib3  = (const float*)d_in[7];
    const float* eW1   = (const float*)d_in[8];
    const float* eb1   = (const float*)d_in[9];
    const float* eW2   = (const float*)d_in[10];
    const float* eb2   = (const float*)d_in[11];
    const float* eW3   = (const float*)d_in[12];
    const float* eb3   = (const float*)d_in[13];
    float* out   = (float*)d_out;
    float* table = (float*)d_ws;  // 2049 floats (+3 pad read) = 8.2 KB

    k1_table_onebody<<<EB + XB, 256, 0, stream>>>(
        x, t, xiW1, xib1, xiW2, xib2, xiW3, xib3,
        eW1, eb1, eW2, eb2, eW3, eb3, out, table);
    k2_twobody<<<256, 256, 0, stream>>>(x, table, out);
}